// Round 4
// baseline (112.043 us; speedup 1.0000x reference)
//
#include <hip/hip_runtime.h>

#define TAU 3.0f
#define FIX 0.2f
#define NPED 1024              // N per batch (reference setup)
#define PEDS_PER_BLOCK 256
#define BLOCK 512
#define GROUPS (BLOCK / 8)                      // 64 peds per pass
#define PASSES (PEDS_PER_BLOCK / GROUPS)        // 4

// Layout: 8 lanes per pedestrian (sub = tid&7), each lane handles 4 neighbors.
// LDS holds the batch's packed (px,py,vx,vy) table; gathers are ds_read_b128.
// idx/mask for pass p+1 are prefetched into registers while computing pass p
// so an HBM load is always in flight (fixes the per-pass vmcnt(0) serialization).
__global__ __launch_bounds__(BLOCK) void rvo_kernel(
    const float* __restrict__ p_cur,     // (B,N,2)
    const float* __restrict__ v_cur,     // (B,N,2)
    const float* __restrict__ v_desire,  // (B,N,2)
    const int*   __restrict__ near_idx,  // (B,N,32)
    const float* __restrict__ mask_arr,  // (B,N,32)
    const int*   __restrict__ cth,       // scalar
    float*       __restrict__ out,       // (B,N,2)
    int N)
{
    __shared__ float4 table[NPED];

    const int tid    = threadIdx.x;
    const int bpb    = N / PEDS_PER_BLOCK;          // blocks per batch = 4
    const int batch  = blockIdx.x / bpb;
    const int pbase  = (blockIdx.x % bpb) * PEDS_PER_BLOCK;

    // ---- stage packed (p,v) table for this batch: coalesced float2 reads ----
    const float2* pb2 = (const float2*)(p_cur) + (size_t)batch * N;
    const float2* vb2 = (const float2*)(v_cur) + (size_t)batch * N;
    #pragma unroll
    for (int n = tid; n < NPED; n += BLOCK) {
        float2 pp = pb2[n];
        float2 vv = vb2[n];
        table[n] = make_float4(pp.x, pp.y, vv.x, vv.y);
    }
    __syncthreads();

    const float thr2 = (float)cth[0] * (float)cth[0];

    const int sub  = tid & 7;        // which 4-neighbor chunk (k = sub*4..sub*4+3)
    const int pgrp = tid >> 3;       // 0..63: pedestrian within pass
    const size_t base = (size_t)batch * N + pbase + pgrp;   // pair at pass p = base + p*64

    const int4*   idx4  = (const int4*)near_idx;
    const float4* msk4  = (const float4*)mask_arr;
    const float2* vd2   = (const float2*)v_desire;

    // prefetch pass 0
    int4   i4 = idx4[base * 8 + sub];
    float4 m4 = msk4[base * 8 + sub];

    #pragma unroll
    for (int pass = 0; pass < PASSES; ++pass) {
        const int4   ci = i4;
        const float4 cm = m4;
        if (pass + 1 < PASSES) {                 // prefetch next pass's stream
            const size_t npair = base + (size_t)(pass + 1) * GROUPS;
            i4 = idx4[npair * 8 + sub];
            m4 = msk4[npair * 8 + sub];
        }

        const int ped  = pbase + pass * GROUPS + pgrp;
        const size_t pair = base + (size_t)pass * GROUPS;

        const float4 self = table[ped];          // broadcast (8 lanes same addr)
        const float2 vd   = vd2[pair];
        const float px = self.x, py = self.y;
        const float vdx = vd.x, vdy = vd.y;

        const int   idxs[4] = {ci.x, ci.y, ci.z, ci.w};
        const float ms[4]   = {cm.x, cm.y, cm.z, cm.w};

        float nx = 0.0f, ny = 0.0f;
        #pragma unroll
        for (int j = 0; j < 4; ++j) {
            const float4 nb = table[idxs[j]];    // LDS gather, ds_read_b128
            const float m = ms[j];
            // rel = self - nb*m, fused: fma(-m, nb, self); neg modifier is free
            const float rpx = fmaf(-m, nb.x, px);
            const float rpy = fmaf(-m, nb.y, py);
            const float rvx = fmaf(-m, nb.z, vdx);
            const float rvy = fmaf(-m, nb.w, vdy);

            const float dpv = fmaf(rpx, rvx, rpy * rvy);
            const float dvv = fmaf(rvx, rvx, fmaf(rvy, rvy, 2e-6f)); // both eps folded
            float t = dpv * __builtin_amdgcn_rcpf(dvv);
            t = fminf(fmaxf(t, 0.0f), TAU);      // inputs finite -> no NaN

            const float cx = fmaf(t, rvx, rpx);
            const float cy = fmaf(t, rvy, rpy);
            const float md2 = fmaf(cx, cx, cy * cy);   // compare squared dist

            const float s = fmaf(rpx, rpx, rpy * rpy);
            // s>0 guard: self-neighbor (s==0, m==1) must contribute exactly 0
            // (ref: 0/(0+1e-6) == 0). rsq rel-err ~1e-7 vs 9.25e-2 threshold.
            const float sel0 = (s > 0.0f) ? __builtin_amdgcn_rsqf(s) : 0.0f;
            const float w    = (md2 < thr2) ? m : 0.0f;  // m in {0,1}: folds mask!=0
            const float sel  = sel0 * w;
            nx = fmaf(-rpy, sel, nx);
            ny = fmaf( rpx, sel, ny);
        }

        // width-8 reduction over sub
        #pragma unroll
        for (int d = 4; d > 0; d >>= 1) {
            nx += __shfl_down(nx, d, 8);
            ny += __shfl_down(ny, d, 8);
        }

        if (sub == 0) {
            ((float2*)out)[pair] = make_float2(fmaf(nx, FIX, vdx),
                                               fmaf(ny, FIX, vdy));
        }
    }
}

extern "C" void kernel_launch(void* const* d_in, const int* in_sizes, int n_in,
                              void* d_out, int out_size, void* d_ws, size_t ws_size,
                              hipStream_t stream) {
    const float* p_cur    = (const float*)d_in[0];
    const float* v_cur    = (const float*)d_in[1];
    const float* v_desire = (const float*)d_in[2];
    const int*   near_idx = (const int*)d_in[3];
    const float* mask_arr = (const float*)d_in[4];
    const int*   cth      = (const int*)d_in[5];
    float*       out      = (float*)d_out;

    const int N  = NPED;
    const int BN = in_sizes[0] / 2;          // B*N pedestrians
    dim3 block(BLOCK);
    dim3 grid(BN / PEDS_PER_BLOCK);          // 1024 blocks for B=256
    rvo_kernel<<<grid, block, 0, stream>>>(p_cur, v_cur, v_desire, near_idx,
                                           mask_arr, cth, out, N);
}

// Round 5
// 106.260 us; speedup vs baseline: 1.0544x; 1.0544x over previous
//
#include <hip/hip_runtime.h>

#define TAU 3.0f
#define FIX 0.2f
#define NPED 1024              // N per batch (reference setup)
#define PEDS_PER_BLOCK 256
#define BLOCK 512
#define GROUPS (BLOCK / 8)                      // 64 peds per pass
#define PASSES (PEDS_PER_BLOCK / GROUPS)        // 4

// Layout: 8 lanes per pedestrian (sub = tid&7), each lane handles 4 neighbors.
// LDS holds the batch's pos/vel tables SPLIT as float2 (bank-conflict relief:
// float4 gathers have conflict class idx%8; float2 gathers idx%16).
__global__ __launch_bounds__(BLOCK) void rvo_kernel(
    const float* __restrict__ p_cur,     // (B,N,2)
    const float* __restrict__ v_cur,     // (B,N,2)
    const float* __restrict__ v_desire,  // (B,N,2)
    const int*   __restrict__ near_idx,  // (B,N,32)
    const float* __restrict__ mask_arr,  // (B,N,32)
    const int*   __restrict__ cth,       // scalar
    float*       __restrict__ out,       // (B,N,2)
    int N)
{
    __shared__ float2 tpos[NPED];
    __shared__ float2 tvel[NPED];

    const int tid    = threadIdx.x;
    const int bpb    = N / PEDS_PER_BLOCK;          // blocks per batch = 4
    const int batch  = blockIdx.x / bpb;
    const int pbase  = (blockIdx.x % bpb) * PEDS_PER_BLOCK;

    // ---- stage pos/vel tables: coalesced float2 reads, stride-1 LDS writes ----
    const float2* pb2 = (const float2*)(p_cur) + (size_t)batch * N;
    const float2* vb2 = (const float2*)(v_cur) + (size_t)batch * N;
    #pragma unroll
    for (int n = tid; n < NPED; n += BLOCK) {
        tpos[n] = pb2[n];
        tvel[n] = vb2[n];
    }
    __syncthreads();

    const float thr2 = (float)cth[0] * (float)cth[0];

    const int sub  = tid & 7;        // which 4-neighbor chunk (k = sub*4..sub*4+3)
    const int pgrp = tid >> 3;       // 0..63: pedestrian within pass

    #pragma unroll
    for (int pass = 0; pass < PASSES; ++pass) {
        const int ped  = pbase + pass * GROUPS + pgrp;
        const size_t pair = (size_t)batch * N + ped;

        // broadcast per-ped scalars (8 lanes same address)
        const float2 self = tpos[ped];
        const float2 vd   = ((const float2*)v_desire)[pair];
        const float px = self.x, py = self.y;
        const float vdx = vd.x, vdy = vd.y;

        // coalesced vector loads: 32 idx/mask per ped = 8 int4/float4
        const int4   i4 = ((const int4*)near_idx)[pair * 8 + sub];
        const float4 m4 = ((const float4*)mask_arr)[pair * 8 + sub];
        const int   idxs[4] = {i4.x, i4.y, i4.z, i4.w};
        const float ms[4]   = {m4.x, m4.y, m4.z, m4.w};

        float nx = 0.0f, ny = 0.0f;
        #pragma unroll
        for (int j = 0; j < 4; ++j) {
            const float2 nbp = tpos[idxs[j]];    // ds_read_b64 gather
            const float2 nbv = tvel[idxs[j]];    // ds_read_b64 gather
            const float m = ms[j];
            // rel = self - nb*m, fused: fma(-m, nb, self)
            const float rpx = fmaf(-m, nbp.x, px);
            const float rpy = fmaf(-m, nbp.y, py);
            const float rvx = fmaf(-m, nbv.x, vdx);
            const float rvy = fmaf(-m, nbv.y, vdy);

            const float dpv = fmaf(rpx, rvx, rpy * rvy);
            const float dvv = fmaf(rvx, rvx, fmaf(rvy, rvy, 2e-6f)); // eps folded
            float t = dpv * __builtin_amdgcn_rcpf(dvv);
            t = fminf(fmaxf(t, 0.0f), TAU);      // inputs finite -> no NaN

            const float cx = fmaf(t, rvx, rpx);
            const float cy = fmaf(t, rvy, rpy);
            const float md2 = fmaf(cx, cx, cy * cy);   // compare squared dist

            const float s = fmaf(rpx, rpx, rpy * rpy);
            // s>0 guard: self-neighbor (s==0, m==1) contributes exactly 0
            // (ref: 0/(0+1e-6) == 0). rsq rel-err ~1e-7 vs 9.25e-2 threshold.
            const float sel0 = (s > 0.0f) ? __builtin_amdgcn_rsqf(s) : 0.0f;
            const float w    = (md2 < thr2) ? m : 0.0f;  // m in {0,1}
            const float sel  = sel0 * w;
            nx = fmaf(-rpy, sel, nx);
            ny = fmaf( rpx, sel, ny);
        }

        // width-8 reduction over sub
        #pragma unroll
        for (int d = 4; d > 0; d >>= 1) {
            nx += __shfl_down(nx, d, 8);
            ny += __shfl_down(ny, d, 8);
        }

        if (sub == 0) {
            ((float2*)out)[pair] = make_float2(fmaf(nx, FIX, vdx),
                                               fmaf(ny, FIX, vdy));
        }
    }
}

extern "C" void kernel_launch(void* const* d_in, const int* in_sizes, int n_in,
                              void* d_out, int out_size, void* d_ws, size_t ws_size,
                              hipStream_t stream) {
    const float* p_cur    = (const float*)d_in[0];
    const float* v_cur    = (const float*)d_in[1];
    const float* v_desire = (const float*)d_in[2];
    const int*   near_idx = (const int*)d_in[3];
    const float* mask_arr = (const float*)d_in[4];
    const int*   cth      = (const int*)d_in[5];
    float*       out      = (float*)d_out;

    const int N  = NPED;
    const int BN = in_sizes[0] / 2;          // B*N pedestrians
    dim3 block(BLOCK);
    dim3 grid(BN / PEDS_PER_BLOCK);          // 1024 blocks for B=256
    rvo_kernel<<<grid, block, 0, stream>>>(p_cur, v_cur, v_desire, near_idx,
                                           mask_arr, cth, out, N);
}